// Round 10
// baseline (147.894 us; speedup 1.0000x reference)
//
#include <hip/hip_runtime.h>
#include <math.h>

#define BQ 8
#define MQ 64
#define KTOP 10
#define EPSQ 1e-7f
#define APBA 256   // anchors per kernel-A block (1/thread)
#define CHUNK 512  // anchors per kernel-B block
#define MBUF 1344  // >= bpbB*KTOP = 670 for N=34000

__device__ __forceinline__ float frcp(float x) { return __builtin_amdgcn_rcpf(x); }

// DFL expected value for one side: 16 coalesced row loads (lane=anchor),
// consumed immediately (low VGPR -> high wave occupancy).
__device__ __forceinline__ float dfl_side(const float* __restrict__ p, size_t Ns) {
  float x0 = p[0];
  float x1 = p[Ns];
  float x2 = p[2 * Ns];
  float x3 = p[3 * Ns];
  float x4 = p[4 * Ns];
  float x5 = p[5 * Ns];
  float x6 = p[6 * Ns];
  float x7 = p[7 * Ns];
  float x8 = p[8 * Ns];
  float x9 = p[9 * Ns];
  float x10 = p[10 * Ns];
  float x11 = p[11 * Ns];
  float x12 = p[12 * Ns];
  float x13 = p[13 * Ns];
  float x14 = p[14 * Ns];
  float x15 = p[15 * Ns];
  float mx = fmaxf(fmaxf(fmaxf(fmaxf(x0, x1), fmaxf(x2, x3)),
                         fmaxf(fmaxf(x4, x5), fmaxf(x6, x7))),
                   fmaxf(fmaxf(fmaxf(x8, x9), fmaxf(x10, x11)),
                         fmaxf(fmaxf(x12, x13), fmaxf(x14, x15))));
  float s = 0.f, ws = 0.f, e;
  e = __expf(x0 - mx); s += e;
  e = __expf(x1 - mx); s += e; ws += 1.f * e;
  e = __expf(x2 - mx); s += e; ws += 2.f * e;
  e = __expf(x3 - mx); s += e; ws += 3.f * e;
  e = __expf(x4 - mx); s += e; ws += 4.f * e;
  e = __expf(x5 - mx); s += e; ws += 5.f * e;
  e = __expf(x6 - mx); s += e; ws += 6.f * e;
  e = __expf(x7 - mx); s += e; ws += 7.f * e;
  e = __expf(x8 - mx); s += e; ws += 8.f * e;
  e = __expf(x9 - mx); s += e; ws += 9.f * e;
  e = __expf(x10 - mx); s += e; ws += 10.f * e;
  e = __expf(x11 - mx); s += e; ws += 11.f * e;
  e = __expf(x12 - mx); s += e; ws += 12.f * e;
  e = __expf(x13 - mx); s += e; ws += 13.f * e;
  e = __expf(x14 - mx); s += e; ws += 14.f * e;
  e = __expf(x15 - mx); s += e; ws += 15.f * e;
  return ws * frcp(s);
}

// ---------------- kernel A: pure DFL decode. NO LDS, NO barriers. ----------------
// Every prior fused variant capped at ~12 barrier-aligned waves/CU; this kernel
// runs up to 32 independent waves/CU so load latency overlaps across waves.
__global__ __launch_bounds__(256) void decode_kernel(
    const float* __restrict__ boxes, const float* __restrict__ scores,
    float4* __restrict__ ev4, unsigned int* __restrict__ iou_bits,
    float* __restrict__ bcePartial, unsigned int* __restrict__ ctr,
    int N, int bpbA) {
  const int tid = threadIdx.x;
  const int b = blockIdx.x / bpbA;
  const int blk = blockIdx.x - b * bpbA;
  const int n = blk * APBA + tid;
  const int w = tid >> 6;
  const int l = tid & 63;
  if (blockIdx.x == 0 && tid == 0) *ctr = 0u;  // merge-done ctr (stream-ordered)

  float bce0 = 0.f;
  if (n < N) {
    const size_t i = (size_t)b * N + n;
    iou_bits[i] = 0u;
    float sc = scores[i];
    bce0 = fmaxf(sc, 0.f) + log1pf(__expf(-fabsf(sc)));
    const size_t Ns = (size_t)N;
    const float* base = boxes + (size_t)(b * 64) * Ns + n;
    float e0 = dfl_side(base, Ns);
    float e1 = dfl_side(base + 16 * Ns, Ns);
    float e2 = dfl_side(base + 32 * Ns, Ns);
    float e3 = dfl_side(base + 48 * Ns, Ns);
    ev4[i] = make_float4(e0, e1, e2, e3);  // dense, coalesced, always-written
  }
#pragma unroll
  for (int d = 1; d < 64; d <<= 1) bce0 += __shfl_xor(bce0, d, 64);
  if (l == 0) bcePartial[blockIdx.x * 4 + w] = bce0;  // per-wave, no LDS/barrier
}

// ---------------- kernel B: screen + per-block per-target top-10 ----------------
__global__ __launch_bounds__(256) void topk_kernel(
    const float4* __restrict__ ev4, const float* __restrict__ targets,
    uint2* __restrict__ cand, int N, int bpbB) {
  const int tid = threadIdx.x;
  const int b = blockIdx.x / bpbB;
  const int blk = blockIdx.x - b * bpbB;
  const int c0 = blk * CHUNK;
  const int w = tid >> 6;
  const int l = tid & 63;

  __shared__ float4 s_sv[CHUNK];
  __shared__ float s_at[CHUNK];
  __shared__ int s_ix[CHUNK];
  __shared__ float s_hv[4 * MQ * KTOP];
  __shared__ int s_hi[4 * MQ * KTOP];
  __shared__ uint2 s_mg[MQ * KTOP];
  __shared__ int s_cnt;
  if (tid == 0) s_cnt = 0;
  __syncthreads();

  // screen 2 anchors/thread from the compact ev4 array (L2/L3-resident)
#pragma unroll
  for (int p = 0; p < CHUNK / 256; ++p) {
    const int n = c0 + p * 256 + tid;
    bool pred = false;
    float4 ev = make_float4(0.f, 0.f, 0.f, 0.f);
    float at = 0.f;
    if (n < N) {
      ev = ev4[(size_t)b * N + n];
      float w1 = ev.z - ev.x, h1 = ev.w - ev.y;
      if (w1 > 0.f && h1 > 0.f) {  // ref masks topv>0; dead anchors never top
        pred = true;
        at = atanf(w1 * frcp(h1 + EPSQ));
      }
    }
    unsigned long long mask = __ballot(pred);
    int cnt = __popcll(mask);
    int bslot = 0;
    if (l == 0 && cnt) bslot = atomicAdd(&s_cnt, cnt);
    bslot = __shfl(bslot, 0, 64);
    if (pred) {
      int pos = bslot + __popcll(mask & ((1ull << l) - 1ull));
      s_sv[pos] = ev;
      s_at[pos] = at;
      s_ix[pos] = n;
    }
  }
  __syncthreads();
  const int nsurv = s_cnt;

  // ---- phase 2: lane = target; wave w scans its survivor quarter ----
  const float4 t = ((const float4*)targets)[b * MQ + l];
  const float x21 = t.x, y21 = t.y, x22 = t.z, y22 = t.w;
  const float w2 = x22 - x21, h2 = y22 - y21;
  const float atan_t = atanf(w2 * frcp(h2 + EPSQ));
  const float area2 = w2 * h2, sumx2 = x21 + x22, sumy2 = y21 + y22;
  const float CPI = 4.0f / (float)(M_PI * M_PI);

  float hv0 = 0.f, hv1 = 0.f, hv2 = 0.f, hv3 = 0.f, hv4 = 0.f;
  float hv5 = 0.f, hv6 = 0.f, hv7 = 0.f, hv8 = 0.f, hv9 = 0.f;
  int hi0 = 0, hi1 = 0, hi2 = 0, hi3 = 0, hi4 = 0;
  int hi5 = 0, hi6 = 0, hi7 = 0, hi8 = 0, hi9 = 0;

  const int qlen = (nsurv + 3) >> 2;
  const int j0 = w * qlen;
  const int j1 = min(nsurv, j0 + qlen);
  for (int j = j0; j < j1; ++j) {
    float4 p = s_sv[j];  // same addr across lanes -> LDS broadcast
    float pa = s_at[j];
    int ixj = s_ix[j];
    float x11 = p.x, y11 = p.y, x12 = p.z, y12 = p.w;
    float w1 = x12 - x11, h1 = y12 - y11;
    float iw = fmaxf(fminf(x12, x22) - fmaxf(x11, x21), 0.f);
    float ih = fmaxf(fminf(y12, y22) - fmaxf(y11, y21), 0.f);
    float inter = iw * ih;
    float uni = w1 * h1 + area2 - inter + EPSQ;
    float iou = inter * frcp(uni);
    float cw = fmaxf(x12, x22) - fminf(x11, x21);
    float ch = fmaxf(y12, y22) - fminf(y11, y21);
    float c2 = cw * cw + ch * ch + EPSQ;
    float dx = sumx2 - x11 - x12;
    float dy = sumy2 - y11 - y12;
    float rho2 = (dx * dx + dy * dy) * 0.25f;
    float da = atan_t - pa;
    float v = CPI * da * da;
    float alpha = v * frcp(v - iou + 1.f + EPSQ);
    float ciou = iou - rho2 * frcp(c2) - alpha * v;
    if (ciou > hv9) {
      float cv = ciou;
      int ci = ixj;
#define INS(vk, ik)                         \
  {                                         \
    bool gt = cv > vk;                      \
    float tv_ = vk; int ti_ = ik;           \
    vk = gt ? cv : vk; ik = gt ? ci : ik;   \
    cv = gt ? tv_ : cv; ci = gt ? ti_ : ci; \
  }
      INS(hv0, hi0) INS(hv1, hi1) INS(hv2, hi2) INS(hv3, hi3) INS(hv4, hi4)
      INS(hv5, hi5) INS(hv6, hi6) INS(hv7, hi7) INS(hv8, hi8) INS(hv9, hi9)
#undef INS
    }
  }
  const int hb = (w * MQ + l) * KTOP;
  s_hv[hb + 0] = hv0; s_hi[hb + 0] = hi0;
  s_hv[hb + 1] = hv1; s_hi[hb + 1] = hi1;
  s_hv[hb + 2] = hv2; s_hi[hb + 2] = hi2;
  s_hv[hb + 3] = hv3; s_hi[hb + 3] = hi3;
  s_hv[hb + 4] = hv4; s_hi[hb + 4] = hi4;
  s_hv[hb + 5] = hv5; s_hi[hb + 5] = hi5;
  s_hv[hb + 6] = hv6; s_hi[hb + 6] = hi6;
  s_hv[hb + 7] = hv7; s_hi[hb + 7] = hi7;
  s_hv[hb + 8] = hv8; s_hi[hb + 8] = hi8;
  s_hv[hb + 9] = hv9; s_hi[hb + 9] = hi9;
  __syncthreads();

  // ---- phase 3: wave 0, lane m: 4-way merge -> s_mg ----
  if (w == 0) {
    const int m = l;
    int p0 = 0, p1 = 0, p2 = 0, p3 = 0;
    for (int r = 0; r < KTOP; ++r) {
      float c0v = s_hv[(0 * MQ + m) * KTOP + p0];
      float c1 = s_hv[(1 * MQ + m) * KTOP + p1];
      float c2m = s_hv[(2 * MQ + m) * KTOP + p2];
      float c3 = s_hv[(3 * MQ + m) * KTOP + p3];
      float best = c0v; int bw = 0;
      if (c1 > best) { best = c1; bw = 1; }
      if (c2m > best) { best = c2m; bw = 2; }
      if (c3 > best) { best = c3; bw = 3; }
      int psel = (bw == 0) ? p0 : (bw == 1) ? p1 : (bw == 2) ? p2 : p3;
      int bidx = s_hi[(bw * MQ + m) * KTOP + psel];
      s_mg[m * KTOP + r] = make_uint2(__float_as_uint(best), (unsigned)bidx);
      if (bw == 0) p0 = min(p0 + 1, KTOP - 1);
      else if (bw == 1) p1 = min(p1 + 1, KTOP - 1);
      else if (bw == 2) p2 = min(p2 + 1, KTOP - 1);
      else p3 = min(p3 + 1, KTOP - 1);
    }
  }
  __syncthreads();
  // copy-out: CONTIGUOUS per-block store (merge takes the strided read side)
  uint2* obase = cand + (size_t)(b * bpbB + blk) * (MQ * KTOP);
  for (int sl = tid; sl < MQ * KTOP; sl += 256) obase[sl] = s_mg[sl];
}

// ---------------- exact top-10 of LDS buffer (wave 0 only) ----------------
__device__ __forceinline__ void select_top10(
    float* s_bv, int* s_bi, float* s_winv, int* s_wini,
    int* s_cnt, int c, int tid) {
  if (tid < 64) {
    for (int r = 0; r < KTOP; ++r) {
      float bv = 0.f;
      int bs = 0xffff;
      for (int sl = tid; sl < c; sl += 64) {
        float v = s_bv[sl];
        if (v > bv) { bv = v; bs = sl; }
      }
      unsigned long long key =
          ((unsigned long long)__float_as_uint(bv) << 32) | (unsigned int)bs;
#pragma unroll
      for (int d = 1; d < 64; d <<= 1) {
        unsigned long long o = __shfl_xor(key, d, 64);
        if (o > key) key = o;
      }
      if (tid == 0) {
        float wv = __uint_as_float((unsigned int)(key >> 32));
        int ws = (int)(key & 0xffffu);
        s_winv[r] = wv;
        if (wv > 0.f && ws != 0xffff) {
          s_wini[r] = s_bi[ws];
          s_bv[ws] = 0.f;
        } else {
          s_wini[r] = 0;
        }
      }
    }
    if (tid < KTOP) { s_bv[tid] = s_winv[tid]; s_bi[tid] = s_wini[tid]; }
    if (tid == 0) *s_cnt = KTOP;
  }
}

// ---------------- kernel C: merge 67x10 per (b,m); scatter + exact delta;
// last block finalizes with a parallel reduction ----------------
__global__ __launch_bounds__(256) void merge_kernel(
    const uint2* __restrict__ cand, const float* __restrict__ scores,
    unsigned int* __restrict__ iou_bits, const float* __restrict__ bcePartial,
    float* __restrict__ mergePartial, unsigned int* __restrict__ ctr,
    float* __restrict__ out, int N, int bpbB, int bpbA) {
  const int bm = blockIdx.x;
  const int b = bm >> 6;
  const int m = bm & 63;
  const int tid = threadIdx.x;
  const int l = tid & 63;
  const int NC = bpbB * KTOP;  // 670 for N=34000

  __shared__ float s_bv[MBUF];
  __shared__ int s_bi[MBUF];
  __shared__ float s_winv[KTOP];
  __shared__ int s_wini[KTOP];
  __shared__ int s_cnt;
  __shared__ float s_d[3];
  __shared__ int s_last;
  __shared__ float s_acc[BQ * 3];  // finalize: {box_sum, npos, bce} per batch
  if (tid == 0) s_cnt = 0;
  if (tid < 3) s_d[tid] = 0.f;
  if (tid < BQ * 3) s_acc[tid] = 0.f;
  __syncthreads();

  // strided gather over topk blocks (cand in contiguous-per-block layout)
  for (int k2 = tid; k2 < NC; k2 += 256) {
    int blkk = k2 / KTOP;
    int r = k2 - blkk * KTOP;
    uint2 e = cand[((size_t)(b * bpbB + blkk) * MQ + m) * KTOP + r];
    float v = __uint_as_float(e.x);
    bool p = v > 0.f;
    unsigned long long mask = __ballot(p);  // lane0 active whenever any lane is
    int cnt = __popcll(mask);
    int bslot = 0;
    if (l == 0 && cnt) bslot = atomicAdd(&s_cnt, cnt);
    bslot = __shfl(bslot, 0, 64);
    if (p) {
      int pos = bslot + __popcll(mask & ((1ull << l) - 1ull));
      s_bv[pos] = v;
      s_bi[pos] = (int)e.y;
    }
  }
  __syncthreads();
  int c = s_cnt;
  __syncthreads();
  if (c > KTOP) {
    select_top10(s_bv, s_bi, s_winv, s_wini, &s_cnt, c, tid);
    __syncthreads();
    c = KTOP;
  }
  if (tid < KTOP && tid < c) {
    float v = s_bv[tid];
    if (v > 0.f) {
      int ix = s_bi[tid];
      unsigned int vb = __float_as_uint(v);
      unsigned int old = atomicMax(&iou_bits[(size_t)b * N + ix], vb);
      if (old < vb) {  // raised this anchor's max: exact delta (telescopes)
        float vold = __uint_as_float(old);  // 0.f when old==0
        bool was = (old != 0u);
        atomicAdd(&s_d[0], was ? (vold - v) : (1.f - v));
        if (!was) atomicAdd(&s_d[1], 1.f);
        atomicAdd(&s_d[2], -scores[(size_t)b * N + ix] * (v - vold));
      }
    }
  }
  __syncthreads();
  if (tid == 0) {
    float4* mp = (float4*)(mergePartial + (size_t)bm * 4);
    *mp = make_float4(s_d[0], s_d[1], s_d[2], 0.f);  // always written
    __threadfence();                                  // release partials
    unsigned int done = atomicAdd(ctr, 1u);           // device-scope RMW
    s_last = (done == (unsigned)(gridDim.x - 1)) ? 1 : 0;
  }
  __syncthreads();
  if (s_last) {
    __threadfence();  // acquire: all other blocks' partials now visible
    volatile const float* mp = mergePartial;
    for (int i = tid; i < BQ * MQ; i += 256) {
      int bb = i >> 6;
      float a0 = mp[i * 4 + 0];
      float a1 = mp[i * 4 + 1];
      float a2 = mp[i * 4 + 2];
      atomicAdd(&s_acc[bb * 3 + 0], a0);
      atomicAdd(&s_acc[bb * 3 + 1], a1);
      atomicAdd(&s_acc[bb * 3 + 2], a2);
    }
    volatile const float* bp = bcePartial;
    const int per_b = bpbA * 4;  // 4 wave-partials per decode block
    for (int i = tid; i < BQ * per_b; i += 256) {
      int bb = i / per_b;
      atomicAdd(&s_acc[bb * 3 + 2], bp[i]);
    }
    __syncthreads();
    if (tid == 0) {
      float box = 0.f, obj = 0.f;
      for (int bb = 0; bb < BQ; ++bb) {
        float np = s_acc[bb * 3 + 1];
        box += (np > 0.f) ? s_acc[bb * 3 + 0] / fmaxf(np, 1.f) : 0.f;
        obj += s_acc[bb * 3 + 2] / (float)N;
      }
      out[0] = (7.5f * box + obj) / (float)BQ;
      out[1] = box;
      out[2] = obj;
    }
  }
}

extern "C" void kernel_launch(void* const* d_in, const int* in_sizes, int n_in,
                              void* d_out, int out_size, void* d_ws, size_t ws_size,
                              hipStream_t stream) {
  const float* boxes = (const float*)d_in[0];
  const float* scores = (const float*)d_in[1];
  const float* targets = (const float*)d_in[2];
  float* out = (float*)d_out;
  const int N = in_sizes[1] / BQ;  // scores is [B, N]

  const int bpbA = (N + APBA - 1) / APBA;   // 133
  const int nblkA = BQ * bpbA;              // 1064 decode blocks (no LDS)
  const int bpbB = (N + CHUNK - 1) / CHUNK; // 67
  const int nblkB = BQ * bpbB;              // 536 topk blocks

  char* ws = (char*)d_ws;
  size_t ev_bytes = (size_t)BQ * N * sizeof(float4);
  size_t cand_bytes = (size_t)BQ * bpbB * MQ * KTOP * sizeof(uint2);
  size_t iou_bytes = (size_t)BQ * N * sizeof(unsigned int);
  size_t bce_bytes = (((size_t)nblkA * 4 * sizeof(float)) + 255) & ~(size_t)255;
  size_t mp_bytes = (size_t)BQ * MQ * 4 * sizeof(float);

  float4* ev4 = (float4*)ws;                   ws += ev_bytes;
  uint2* cand = (uint2*)ws;                    ws += cand_bytes;
  unsigned int* iou_bits = (unsigned int*)ws;  ws += iou_bytes;
  float* bcePartial = (float*)ws;              ws += bce_bytes;
  float* mergePartial = (float*)ws;            ws += mp_bytes;
  unsigned int* ctr = (unsigned int*)ws;

  // 3 dispatches: A (pure decode, no LDS/barriers) -> B (screen+topk) -> C
  // (merge + last-block finalize). No memsets: all partials always-written;
  // ctr zeroed by A, consumed by C (stream-ordered).
  decode_kernel<<<nblkA, 256, 0, stream>>>(boxes, scores, ev4, iou_bits,
                                           bcePartial, ctr, N, bpbA);
  topk_kernel<<<nblkB, 256, 0, stream>>>(ev4, targets, cand, N, bpbB);
  merge_kernel<<<BQ * MQ, 256, 0, stream>>>(cand, scores, iou_bits, bcePartial,
                                            mergePartial, ctr, out, N, bpbB, bpbA);
}

// Round 11
// 143.921 us; speedup vs baseline: 1.0276x; 1.0276x over previous
//
#include <hip/hip_runtime.h>
#include <math.h>

#define BQ 8
#define MQ 64
#define KTOP 10
#define EPSQ 1e-7f
#define CHUNKA 1024  // anchors per decode block (x 16 rows = 64KB tile)
#define CHUNKB 512   // anchors per topk block
#define MBUF 1344    // >= bpbB*KTOP = 670 for N=34000

__device__ __forceinline__ float frcp(float x) { return __builtin_amdgcn_rcpf(x); }

// ---------------- kernel A: decode with 4KB DRAM runs ----------------
// block = (b, side, 1024-anchor chunk). Stages [16 rows x 1024 anchors] into
// LDS via 4 back-to-back global_load_lds_dwordx4 per row with all 64 lanes
// CONTIGUOUS (1KB/inst, 4KB/row run). Every prior variant issued 256B (or
// 64B) runs per row -> ~25% DRAM page efficiency; this is the run-length fix.
__global__ __launch_bounds__(256) void decode_kernel(
    const float* __restrict__ boxes, const float* __restrict__ scores,
    float* __restrict__ evs,  // planar [4][BQ*N]
    unsigned int* __restrict__ iou_bits, float* __restrict__ bcePartial,
    unsigned int* __restrict__ ctr, int N, int nchunk) {
  const int tid = threadIdx.x;
  const int w = tid >> 6;
  const int l = tid & 63;
  int t = blockIdx.x;
  const int c = t % nchunk;
  t /= nchunk;
  const int s = t & 3;
  const int b = t >> 2;
  const int c0 = c * CHUNKA;

  __shared__ __align__(16) float tile[16][CHUNKA];  // 64KB -> 2 blocks/CU

  if (blockIdx.x == 0 && tid == 0) *ctr = 0u;  // merge-done ctr; stream-ordered

  const size_t Ns = (size_t)N;
  const size_t BN = (size_t)BQ * N;

  // ---- stage: wave w owns rows 4w..4w+3; 4 contiguous 1KB insts per row ----
#pragma unroll
  for (int rr = 0; rr < 4; ++rr) {
    const int r = 4 * w + rr;
    const float* rowg = boxes + (size_t)(b * 64 + s * 16 + r) * Ns;
#pragma unroll
    for (int k = 0; k < 4; ++k) {
      int fi = c0 + k * 256 + l * 4;      // lane-contiguous float index
      if (fi > N - 4) fi = N - 4;         // tail dup-clamp; cols >= N unused
      __builtin_amdgcn_global_load_lds(
          (const __attribute__((address_space(1))) void*)(rowg + fi),
          (__attribute__((address_space(3))) void*)&tile[r][k * 256],
          16, 0, 0);  // lds dest = uniform base + lane*16 (linear)
    }
  }
  // overlap with stage: BCE + iou init (side-0 blocks own the score work)
  float bce0 = 0.f;
  if (s == 0) {
#pragma unroll
    for (int p = 0; p < 4; ++p) {
      const int n = c0 + p * 256 + tid;
      if (n < N) {
        const size_t i = (size_t)b * N + n;
        iou_bits[i] = 0u;
        float sc = scores[i];
        bce0 += fmaxf(sc, 0.f) + log1pf(__expf(-fabsf(sc)));
      }
    }
#pragma unroll
    for (int d = 1; d < 64; d <<= 1) bce0 += __shfl_xor(bce0, d, 64);
    if (l == 0) bcePartial[(size_t)(b * nchunk + c) * 4 + w] = bce0;
  }
  asm volatile("s_waitcnt vmcnt(0)" ::: "memory");
  __syncthreads();

  // ---- compute: 4 anchors/thread, lane-consecutive LDS columns ----
#pragma unroll
  for (int p = 0; p < 4; ++p) {
    const int col = p * 256 + tid;
    const int n = c0 + col;
    float x0 = tile[0][col], x1 = tile[1][col], x2 = tile[2][col],
          x3 = tile[3][col], x4 = tile[4][col], x5 = tile[5][col],
          x6 = tile[6][col], x7 = tile[7][col], x8 = tile[8][col],
          x9 = tile[9][col], x10 = tile[10][col], x11 = tile[11][col],
          x12 = tile[12][col], x13 = tile[13][col], x14 = tile[14][col],
          x15 = tile[15][col];
    float mx = fmaxf(fmaxf(fmaxf(fmaxf(x0, x1), fmaxf(x2, x3)),
                           fmaxf(fmaxf(x4, x5), fmaxf(x6, x7))),
                     fmaxf(fmaxf(fmaxf(x8, x9), fmaxf(x10, x11)),
                           fmaxf(fmaxf(x12, x13), fmaxf(x14, x15))));
    float sm = 0.f, ws = 0.f, e;
    e = __expf(x0 - mx); sm += e;
    e = __expf(x1 - mx); sm += e; ws += 1.f * e;
    e = __expf(x2 - mx); sm += e; ws += 2.f * e;
    e = __expf(x3 - mx); sm += e; ws += 3.f * e;
    e = __expf(x4 - mx); sm += e; ws += 4.f * e;
    e = __expf(x5 - mx); sm += e; ws += 5.f * e;
    e = __expf(x6 - mx); sm += e; ws += 6.f * e;
    e = __expf(x7 - mx); sm += e; ws += 7.f * e;
    e = __expf(x8 - mx); sm += e; ws += 8.f * e;
    e = __expf(x9 - mx); sm += e; ws += 9.f * e;
    e = __expf(x10 - mx); sm += e; ws += 10.f * e;
    e = __expf(x11 - mx); sm += e; ws += 11.f * e;
    e = __expf(x12 - mx); sm += e; ws += 12.f * e;
    e = __expf(x13 - mx); sm += e; ws += 13.f * e;
    e = __expf(x14 - mx); sm += e; ws += 14.f * e;
    e = __expf(x15 - mx); sm += e; ws += 15.f * e;
    if (n < N) evs[(size_t)s * BN + (size_t)b * N + n] = ws * frcp(sm);
  }
}

// ---------------- kernel B: screen + per-block per-target top-10 ----------------
__global__ __launch_bounds__(256) void topk_kernel(
    const float* __restrict__ evs, const float* __restrict__ targets,
    uint2* __restrict__ cand, int N, int bpbB) {
  const int tid = threadIdx.x;
  const int b = blockIdx.x / bpbB;
  const int blk = blockIdx.x - b * bpbB;
  const int c0 = blk * CHUNKB;
  const int w = tid >> 6;
  const int l = tid & 63;
  const size_t BN = (size_t)BQ * N;

  __shared__ float4 s_sv[CHUNKB];
  __shared__ float s_at[CHUNKB];
  __shared__ int s_ix[CHUNKB];
  __shared__ float s_hv[4 * MQ * KTOP];
  __shared__ int s_hi[4 * MQ * KTOP];
  __shared__ uint2 s_mg[MQ * KTOP];
  __shared__ int s_cnt;
  if (tid == 0) s_cnt = 0;
  __syncthreads();

#pragma unroll
  for (int p = 0; p < CHUNKB / 256; ++p) {
    const int n = c0 + p * 256 + tid;
    bool pred = false;
    float4 ev = make_float4(0.f, 0.f, 0.f, 0.f);
    float at = 0.f;
    if (n < N) {
      const size_t i = (size_t)b * N + n;
      ev.x = evs[0 * BN + i];
      ev.y = evs[1 * BN + i];
      ev.z = evs[2 * BN + i];
      ev.w = evs[3 * BN + i];
      float w1 = ev.z - ev.x, h1 = ev.w - ev.y;
      if (w1 > 0.f && h1 > 0.f) {  // ref masks topv>0; dead anchors never top
        pred = true;
        at = atanf(w1 * frcp(h1 + EPSQ));
      }
    }
    unsigned long long mask = __ballot(pred);
    int cnt = __popcll(mask);
    int bslot = 0;
    if (l == 0 && cnt) bslot = atomicAdd(&s_cnt, cnt);
    bslot = __shfl(bslot, 0, 64);
    if (pred) {
      int pos = bslot + __popcll(mask & ((1ull << l) - 1ull));
      s_sv[pos] = ev;
      s_at[pos] = at;
      s_ix[pos] = n;
    }
  }
  __syncthreads();
  const int nsurv = s_cnt;

  // ---- phase 2: lane = target; wave w scans its survivor quarter ----
  const float4 t = ((const float4*)targets)[b * MQ + l];
  const float x21 = t.x, y21 = t.y, x22 = t.z, y22 = t.w;
  const float w2 = x22 - x21, h2 = y22 - y21;
  const float atan_t = atanf(w2 * frcp(h2 + EPSQ));
  const float area2 = w2 * h2, sumx2 = x21 + x22, sumy2 = y21 + y22;
  const float CPI = 4.0f / (float)(M_PI * M_PI);

  float hv0 = 0.f, hv1 = 0.f, hv2 = 0.f, hv3 = 0.f, hv4 = 0.f;
  float hv5 = 0.f, hv6 = 0.f, hv7 = 0.f, hv8 = 0.f, hv9 = 0.f;
  int hi0 = 0, hi1 = 0, hi2 = 0, hi3 = 0, hi4 = 0;
  int hi5 = 0, hi6 = 0, hi7 = 0, hi8 = 0, hi9 = 0;

  const int qlen = (nsurv + 3) >> 2;
  const int j0 = w * qlen;
  const int j1 = min(nsurv, j0 + qlen);
  for (int j = j0; j < j1; ++j) {
    float4 p = s_sv[j];  // same addr across lanes -> LDS broadcast
    float pa = s_at[j];
    int ixj = s_ix[j];
    float x11 = p.x, y11 = p.y, x12 = p.z, y12 = p.w;
    float w1 = x12 - x11, h1 = y12 - y11;
    float iw = fmaxf(fminf(x12, x22) - fmaxf(x11, x21), 0.f);
    float ih = fmaxf(fminf(y12, y22) - fmaxf(y11, y21), 0.f);
    float inter = iw * ih;
    float uni = w1 * h1 + area2 - inter + EPSQ;
    float iou = inter * frcp(uni);
    float cw = fmaxf(x12, x22) - fminf(x11, x21);
    float ch = fmaxf(y12, y22) - fminf(y11, y21);
    float c2 = cw * cw + ch * ch + EPSQ;
    float dx = sumx2 - x11 - x12;
    float dy = sumy2 - y11 - y12;
    float rho2 = (dx * dx + dy * dy) * 0.25f;
    float da = atan_t - pa;
    float v = CPI * da * da;
    float alpha = v * frcp(v - iou + 1.f + EPSQ);
    float ciou = iou - rho2 * frcp(c2) - alpha * v;
    if (ciou > hv9) {
      float cv = ciou;
      int ci = ixj;
#define INS(vk, ik)                         \
  {                                         \
    bool gt = cv > vk;                      \
    float tv_ = vk; int ti_ = ik;           \
    vk = gt ? cv : vk; ik = gt ? ci : ik;   \
    cv = gt ? tv_ : cv; ci = gt ? ti_ : ci; \
  }
      INS(hv0, hi0) INS(hv1, hi1) INS(hv2, hi2) INS(hv3, hi3) INS(hv4, hi4)
      INS(hv5, hi5) INS(hv6, hi6) INS(hv7, hi7) INS(hv8, hi8) INS(hv9, hi9)
#undef INS
    }
  }
  const int hb = (w * MQ + l) * KTOP;
  s_hv[hb + 0] = hv0; s_hi[hb + 0] = hi0;
  s_hv[hb + 1] = hv1; s_hi[hb + 1] = hi1;
  s_hv[hb + 2] = hv2; s_hi[hb + 2] = hi2;
  s_hv[hb + 3] = hv3; s_hi[hb + 3] = hi3;
  s_hv[hb + 4] = hv4; s_hi[hb + 4] = hi4;
  s_hv[hb + 5] = hv5; s_hi[hb + 5] = hi5;
  s_hv[hb + 6] = hv6; s_hi[hb + 6] = hi6;
  s_hv[hb + 7] = hv7; s_hi[hb + 7] = hi7;
  s_hv[hb + 8] = hv8; s_hi[hb + 8] = hi8;
  s_hv[hb + 9] = hv9; s_hi[hb + 9] = hi9;
  __syncthreads();

  // ---- phase 3: wave 0, lane m: 4-way merge -> s_mg ----
  if (w == 0) {
    const int m = l;
    int p0 = 0, p1 = 0, p2 = 0, p3 = 0;
    for (int r = 0; r < KTOP; ++r) {
      float c0v = s_hv[(0 * MQ + m) * KTOP + p0];
      float c1 = s_hv[(1 * MQ + m) * KTOP + p1];
      float c2m = s_hv[(2 * MQ + m) * KTOP + p2];
      float c3 = s_hv[(3 * MQ + m) * KTOP + p3];
      float best = c0v; int bw = 0;
      if (c1 > best) { best = c1; bw = 1; }
      if (c2m > best) { best = c2m; bw = 2; }
      if (c3 > best) { best = c3; bw = 3; }
      int psel = (bw == 0) ? p0 : (bw == 1) ? p1 : (bw == 2) ? p2 : p3;
      int bidx = s_hi[(bw * MQ + m) * KTOP + psel];
      s_mg[m * KTOP + r] = make_uint2(__float_as_uint(best), (unsigned)bidx);
      if (bw == 0) p0 = min(p0 + 1, KTOP - 1);
      else if (bw == 1) p1 = min(p1 + 1, KTOP - 1);
      else if (bw == 2) p2 = min(p2 + 1, KTOP - 1);
      else p3 = min(p3 + 1, KTOP - 1);
    }
  }
  __syncthreads();
  uint2* obase = cand + (size_t)(b * bpbB + blk) * (MQ * KTOP);
  for (int sl = tid; sl < MQ * KTOP; sl += 256) obase[sl] = s_mg[sl];
}

// ---------------- exact top-10 of LDS buffer (wave 0 only) ----------------
__device__ __forceinline__ void select_top10(
    float* s_bv, int* s_bi, float* s_winv, int* s_wini,
    int* s_cnt, int c, int tid) {
  if (tid < 64) {
    for (int r = 0; r < KTOP; ++r) {
      float bv = 0.f;
      int bs = 0xffff;
      for (int sl = tid; sl < c; sl += 64) {
        float v = s_bv[sl];
        if (v > bv) { bv = v; bs = sl; }
      }
      unsigned long long key =
          ((unsigned long long)__float_as_uint(bv) << 32) | (unsigned int)bs;
#pragma unroll
      for (int d = 1; d < 64; d <<= 1) {
        unsigned long long o = __shfl_xor(key, d, 64);
        if (o > key) key = o;
      }
      if (tid == 0) {
        float wv = __uint_as_float((unsigned int)(key >> 32));
        int ws = (int)(key & 0xffffu);
        s_winv[r] = wv;
        if (wv > 0.f && ws != 0xffff) {
          s_wini[r] = s_bi[ws];
          s_bv[ws] = 0.f;
        } else {
          s_wini[r] = 0;
        }
      }
    }
    if (tid < KTOP) { s_bv[tid] = s_winv[tid]; s_bi[tid] = s_wini[tid]; }
    if (tid == 0) *s_cnt = KTOP;
  }
}

// ---------------- kernel C: merge; scatter + exact delta; last block finalizes ----------------
__global__ __launch_bounds__(256) void merge_kernel(
    const uint2* __restrict__ cand, const float* __restrict__ scores,
    unsigned int* __restrict__ iou_bits, const float* __restrict__ bcePartial,
    float* __restrict__ mergePartial, unsigned int* __restrict__ ctr,
    float* __restrict__ out, int N, int bpbB, int nchunk) {
  const int bm = blockIdx.x;
  const int b = bm >> 6;
  const int m = bm & 63;
  const int tid = threadIdx.x;
  const int l = tid & 63;
  const int NC = bpbB * KTOP;  // 670 for N=34000

  __shared__ float s_bv[MBUF];
  __shared__ int s_bi[MBUF];
  __shared__ float s_winv[KTOP];
  __shared__ int s_wini[KTOP];
  __shared__ int s_cnt;
  __shared__ float s_d[3];
  __shared__ int s_last;
  __shared__ float s_acc[BQ * 3];
  if (tid == 0) s_cnt = 0;
  if (tid < 3) s_d[tid] = 0.f;
  if (tid < BQ * 3) s_acc[tid] = 0.f;
  __syncthreads();

  for (int k2 = tid; k2 < NC; k2 += 256) {
    int blkk = k2 / KTOP;
    int r = k2 - blkk * KTOP;
    uint2 e = cand[((size_t)(b * bpbB + blkk) * MQ + m) * KTOP + r];
    float v = __uint_as_float(e.x);
    bool p = v > 0.f;
    unsigned long long mask = __ballot(p);
    int cnt = __popcll(mask);
    int bslot = 0;
    if (l == 0 && cnt) bslot = atomicAdd(&s_cnt, cnt);
    bslot = __shfl(bslot, 0, 64);
    if (p) {
      int pos = bslot + __popcll(mask & ((1ull << l) - 1ull));
      s_bv[pos] = v;
      s_bi[pos] = (int)e.y;
    }
  }
  __syncthreads();
  int c = s_cnt;
  __syncthreads();
  if (c > KTOP) {
    select_top10(s_bv, s_bi, s_winv, s_wini, &s_cnt, c, tid);
    __syncthreads();
    c = KTOP;
  }
  if (tid < KTOP && tid < c) {
    float v = s_bv[tid];
    if (v > 0.f) {
      int ix = s_bi[tid];
      unsigned int vb = __float_as_uint(v);
      unsigned int old = atomicMax(&iou_bits[(size_t)b * N + ix], vb);
      if (old < vb) {
        float vold = __uint_as_float(old);
        bool was = (old != 0u);
        atomicAdd(&s_d[0], was ? (vold - v) : (1.f - v));
        if (!was) atomicAdd(&s_d[1], 1.f);
        atomicAdd(&s_d[2], -scores[(size_t)b * N + ix] * (v - vold));
      }
    }
  }
  __syncthreads();
  if (tid == 0) {
    float4* mp = (float4*)(mergePartial + (size_t)bm * 4);
    *mp = make_float4(s_d[0], s_d[1], s_d[2], 0.f);
    __threadfence();
    unsigned int done = atomicAdd(ctr, 1u);
    s_last = (done == (unsigned)(gridDim.x - 1)) ? 1 : 0;
  }
  __syncthreads();
  if (s_last) {
    __threadfence();
    volatile const float* mp = mergePartial;
    for (int i = tid; i < BQ * MQ; i += 256) {
      int bb = i >> 6;
      float a0 = mp[i * 4 + 0];
      float a1 = mp[i * 4 + 1];
      float a2 = mp[i * 4 + 2];
      atomicAdd(&s_acc[bb * 3 + 0], a0);
      atomicAdd(&s_acc[bb * 3 + 1], a1);
      atomicAdd(&s_acc[bb * 3 + 2], a2);
    }
    volatile const float* bp = bcePartial;
    const int per_b = nchunk * 4;  // 4 wave-partials per side-0 decode block
    for (int i = tid; i < BQ * per_b; i += 256) {
      int bb = i / per_b;
      atomicAdd(&s_acc[bb * 3 + 2], bp[i]);
    }
    __syncthreads();
    if (tid == 0) {
      float box = 0.f, obj = 0.f;
      for (int bb = 0; bb < BQ; ++bb) {
        float np = s_acc[bb * 3 + 1];
        box += (np > 0.f) ? s_acc[bb * 3 + 0] / fmaxf(np, 1.f) : 0.f;
        obj += s_acc[bb * 3 + 2] / (float)N;
      }
      out[0] = (7.5f * box + obj) / (float)BQ;
      out[1] = box;
      out[2] = obj;
    }
  }
}

extern "C" void kernel_launch(void* const* d_in, const int* in_sizes, int n_in,
                              void* d_out, int out_size, void* d_ws, size_t ws_size,
                              hipStream_t stream) {
  const float* boxes = (const float*)d_in[0];
  const float* scores = (const float*)d_in[1];
  const float* targets = (const float*)d_in[2];
  float* out = (float*)d_out;
  const int N = in_sizes[1] / BQ;  // scores is [B, N]

  const int nchunk = (N + CHUNKA - 1) / CHUNKA;  // 34
  const int nblkA = BQ * 4 * nchunk;             // 1088 decode blocks
  const int bpbB = (N + CHUNKB - 1) / CHUNKB;    // 67
  const int nblkB = BQ * bpbB;                   // 536 topk blocks

  char* ws = (char*)d_ws;
  size_t evs_bytes = (size_t)4 * BQ * N * sizeof(float);
  size_t cand_bytes = (size_t)BQ * bpbB * MQ * KTOP * sizeof(uint2);
  size_t iou_bytes = (size_t)BQ * N * sizeof(unsigned int);
  size_t bce_bytes = (((size_t)BQ * nchunk * 4 * sizeof(float)) + 255) & ~(size_t)255;
  size_t mp_bytes = (size_t)BQ * MQ * 4 * sizeof(float);

  float* evs = (float*)ws;                     ws += evs_bytes;
  uint2* cand = (uint2*)ws;                    ws += cand_bytes;
  unsigned int* iou_bits = (unsigned int*)ws;  ws += iou_bytes;
  float* bcePartial = (float*)ws;              ws += bce_bytes;
  float* mergePartial = (float*)ws;            ws += mp_bytes;
  unsigned int* ctr = (unsigned int*)ws;

  // 3 dispatches: A (4KB-run staged decode) -> B (screen+topk) -> C (merge +
  // last-block finalize). No memsets: partials always-written; ctr zeroed by
  // A block 0, consumed by C (stream-ordered).
  decode_kernel<<<nblkA, 256, 0, stream>>>(boxes, scores, evs, iou_bits,
                                           bcePartial, ctr, N, nchunk);
  topk_kernel<<<nblkB, 256, 0, stream>>>(evs, targets, cand, N, bpbB);
  merge_kernel<<<BQ * MQ, 256, 0, stream>>>(cand, scores, iou_bits, bcePartial,
                                            mergePartial, ctr, out, N, bpbB, nchunk);
}